// Round 1
// baseline (405.835 us; speedup 1.0000x reference)
//
#include <hip/hip_runtime.h>
#include <math.h>

// QRNN: B=8, T=4096, C=256, UNITS=256, WINDOW=2
// gates[b,t,:] = x[b,t-1,:]@K[0] + x[b,t,:]@K[1] + bias   (x[-1]=0)
// z=tanh, f=sigm, o=sigm;  c_t = f*c_{t-1} + (1-f)*z_t;  h = o*c

#define Bq 8
#define Tq 4096
#define Cq 256
#define Uq 256
#define Gq 768
#define NCq 64   // chunks per sequence
#define Lq 64    // chunk length (T/NC)

__device__ __forceinline__ float sigmoidf_(float x) {
    return 1.f / (1.f + __expf(-x));
}
__device__ __forceinline__ float tanh_fast(float x) {
    return 1.f - 2.f / (__expf(2.f * x) + 1.f);
}

// ---------------- Kernel 1: conv (as GEMM M=32768,K=512,N=768) + activations
// tile 64x64, 256 threads, 4x4 acc/thread, LDS-staged A(transposed) and B.
__global__ __launch_bounds__(256) void conv_gates(
    const float* __restrict__ x, const float* __restrict__ kw,
    const float* __restrict__ bias, float* __restrict__ Z,
    float* __restrict__ F, float* __restrict__ O)
{
    __shared__ float As[64][68];   // [k][row]
    __shared__ float Bs[64][68];   // [k][col]
    const int tid = threadIdx.x;
    const int mt  = blockIdx.x;          // 0..511  (M tiles)
    const int n0  = blockIdx.y << 6;     // 0..704  (N tile start)
    const int b   = mt >> 6;             // 64 M-tiles per batch
    const int t0  = (mt & 63) << 6;
    const int ty  = tid >> 4, tx = tid & 15;

    float acc[4][4];
    #pragma unroll
    for (int i = 0; i < 4; ++i)
        #pragma unroll
        for (int j = 0; j < 4; ++j) acc[i][j] = 0.f;

    for (int kk = 0; kk < 8; ++kk) {
        const int koff = (kk & 3) << 6;      // channel offset within x row
        const int tsh  = (kk < 4) ? -1 : 0;  // window 0 uses x[t-1]
        // stage A: As[k][r] = x[b][t0+r+tsh][koff+k]
        #pragma unroll
        for (int i = 0; i < 4; ++i) {
            int f4 = tid + (i << 8);         // 0..1023 float4 slots
            int r = f4 >> 4, c4 = f4 & 15;
            int trow = t0 + r + tsh;
            float4 v = make_float4(0.f, 0.f, 0.f, 0.f);
            if (trow >= 0)
                v = *(const float4*)&x[(((size_t)b << 12) + trow) * 256 + koff + (c4 << 2)];
            int cc = c4 << 2;
            As[cc + 0][r] = v.x; As[cc + 1][r] = v.y;
            As[cc + 2][r] = v.z; As[cc + 3][r] = v.w;
        }
        // stage B: Bs[k][c] = kw[kk*64+k][n0+c]
        #pragma unroll
        for (int i = 0; i < 4; ++i) {
            int f4 = tid + (i << 8);
            int k = f4 >> 4, c4 = f4 & 15;
            float4 v = *(const float4*)&kw[(size_t)((kk << 6) + k) * 768 + n0 + (c4 << 2)];
            *(float4*)&Bs[k][c4 << 2] = v;
        }
        __syncthreads();
        #pragma unroll 8
        for (int k = 0; k < 64; ++k) {
            float4 av = *(const float4*)&As[k][ty << 2];
            float4 bv = *(const float4*)&Bs[k][tx << 2];
            float a[4] = {av.x, av.y, av.z, av.w};
            float bq[4] = {bv.x, bv.y, bv.z, bv.w};
            #pragma unroll
            for (int i = 0; i < 4; ++i)
                #pragma unroll
                for (int j = 0; j < 4; ++j)
                    acc[i][j] = fmaf(a[i], bq[j], acc[i][j]);
        }
        __syncthreads();
    }

    float4 bv4 = *(const float4*)&bias[n0 + (tx << 2)];
    const float bb[4] = {bv4.x, bv4.y, bv4.z, bv4.w};
    const int cg = n0 + (tx << 2);
    #pragma unroll
    for (int i = 0; i < 4; ++i) {
        int t = t0 + (ty << 2) + i;
        size_t rb = (((size_t)b << 12) + t) * 256;
        float g[4];
        #pragma unroll
        for (int j = 0; j < 4; ++j) g[j] = acc[i][j] + bb[j];
        float4 r;
        if (n0 < 256) {
            r.x = tanh_fast(g[0]); r.y = tanh_fast(g[1]);
            r.z = tanh_fast(g[2]); r.w = tanh_fast(g[3]);
            *(float4*)&Z[rb + cg] = r;
        } else if (n0 < 512) {
            r.x = sigmoidf_(g[0]); r.y = sigmoidf_(g[1]);
            r.z = sigmoidf_(g[2]); r.w = sigmoidf_(g[3]);
            *(float4*)&F[rb + cg - 256] = r;
        } else {
            r.x = sigmoidf_(g[0]); r.y = sigmoidf_(g[1]);
            r.z = sigmoidf_(g[2]); r.w = sigmoidf_(g[3]);
            *(float4*)&O[rb + cg - 512] = r;
        }
    }
}

// ---------------- Kernel 2: per-chunk fold (A_prod, B_acc)
__global__ __launch_bounds__(256) void chunk_reduce(
    const float* __restrict__ Z, const float* __restrict__ F,
    float* __restrict__ CA, float* __restrict__ CB)
{
    const int u = threadIdx.x;
    const int blk = blockIdx.x;          // 0..511
    const int b = blk >> 6, ck = blk & 63;
    size_t base = (((size_t)b << 12) + ck * Lq) * 256 + u;
    float A = 1.f, Bv = 0.f;
    #pragma unroll 8
    for (int s = 0; s < Lq; ++s) {
        float f = F[base + (size_t)s * 256];
        float z = Z[base + (size_t)s * 256];
        Bv = fmaf(f, Bv, (1.f - f) * z);
        A *= f;
    }
    size_t cidx = ((size_t)b * NCq + ck) * 256 + u;
    CA[cidx] = A;
    CB[cidx] = Bv;
}

// ---------------- Kernel 3: sequential scan over chunk carries (tiny)
__global__ __launch_bounds__(256) void carry_scan(
    const float* __restrict__ CA, const float* __restrict__ CB,
    float* __restrict__ CIN)
{
    const int u = threadIdx.x;
    const int b = blockIdx.x;
    float c = 0.f;
    #pragma unroll 8
    for (int k = 0; k < NCq; ++k) {
        size_t idx = ((size_t)b * NCq + k) * 256 + u;
        CIN[idx] = c;
        c = fmaf(CA[idx], c, CB[idx]);
    }
}

// ---------------- Kernel 4: apply carry, rebuild c, h = sigm(o)*c
__global__ __launch_bounds__(256) void apply_scan(
    const float* __restrict__ Z, const float* __restrict__ F,
    const float* __restrict__ CIN, float* __restrict__ O)
{
    const int u = threadIdx.x;
    const int blk = blockIdx.x;
    const int b = blk >> 6, ck = blk & 63;
    float c = CIN[((size_t)b * NCq + ck) * 256 + u];
    size_t base = (((size_t)b << 12) + ck * Lq) * 256 + u;
    #pragma unroll 8
    for (int s = 0; s < Lq; ++s) {
        size_t idx = base + (size_t)s * 256;
        float f = F[idx], z = Z[idx];
        c = fmaf(f, c, (1.f - f) * z);
        O[idx] = O[idx] * c;
    }
}

extern "C" void kernel_launch(void* const* d_in, const int* in_sizes, int n_in,
                              void* d_out, int out_size, void* d_ws, size_t ws_size,
                              hipStream_t stream) {
    const float* x    = (const float*)d_in[0];
    const float* kw   = (const float*)d_in[1];
    const float* bias = (const float*)d_in[2];
    float* out = (float*)d_out;
    float* ws  = (float*)d_ws;

    const size_t BTU = (size_t)Bq * Tq * Uq;          // 8,388,608
    float* Z   = ws;
    float* F   = ws + BTU;
    float* CA  = ws + 2 * BTU;
    float* CB  = CA + (size_t)Bq * NCq * Uq;          // 131072 each
    float* CIN = CB + (size_t)Bq * NCq * Uq;

    dim3 g1(512, 12);
    conv_gates<<<g1, 256, 0, stream>>>(x, kw, bias, Z, F, out);
    chunk_reduce<<<512, 256, 0, stream>>>(Z, F, CA, CB);
    carry_scan<<<Bq, 256, 0, stream>>>(CA, CB, CIN);
    apply_scan<<<512, 256, 0, stream>>>(Z, F, CIN, out);
}

// Round 2
// 147.341 us; speedup vs baseline: 2.7544x; 2.7544x over previous
//
#include <hip/hip_runtime.h>
#include <math.h>

// QRNN: B=8, T=4096, C=256, UNITS=256, WINDOW=2
// gates = concat(x[t-1],x[t]) @ K[512,768] + bias ; z=tanh f=sig o=sig
// c_t = f*c_{t-1} + (1-f)*z_t ; h = sig(o)*c
// GEMM M=32768 K=512 N=768 done in bf16 MFMA with hi/lo split (3 passes).

#define Bq 8
#define Tq 4096
#define NCq 64
#define Lq 64

typedef __attribute__((ext_vector_type(8))) short bf16x8;
typedef __attribute__((ext_vector_type(4))) float f32x4;

__device__ __forceinline__ float sigmoidf_(float x) {
    return 1.f / (1.f + __expf(-x));
}
__device__ __forceinline__ float tanh_fast(float x) {
    return 1.f - 2.f / (__expf(2.f * x) + 1.f);
}
__device__ __forceinline__ unsigned short f2bf(float f) {
    unsigned u = __float_as_uint(f);
    unsigned r = (u + 0x7fffu + ((u >> 16) & 1u)) >> 16;
    return (unsigned short)r;
}
__device__ __forceinline__ float bf2f(unsigned short h) {
    return __uint_as_float(((unsigned)h) << 16);
}
__device__ __forceinline__ void gload16(const void* g, void* l) {
    __builtin_amdgcn_global_load_lds(
        (const __attribute__((address_space(1))) void*)g,
        (__attribute__((address_space(3))) void*)l, 16, 0, 0);
}

// ---------- prep 1: x -> padded bf16 hi/lo  (xp[b][tp][c], tp=t+1, row 0 = zeros)
__global__ __launch_bounds__(256) void split_x(
    const float* __restrict__ x, unsigned short* __restrict__ xh,
    unsigned short* __restrict__ xl)
{
    int idx = blockIdx.x * 256 + threadIdx.x;      // one per 4 elems
    if (idx >= Bq * 4097 * 64) return;
    int b  = idx / (4097 * 64);
    int r  = idx % (4097 * 64);
    int tp = r / 64, c4 = (r % 64) << 2;
    size_t o = ((size_t)(b * 4097 + tp) << 8) + c4;
    ushort4 h = make_ushort4(0, 0, 0, 0), lo = h;
    if (tp > 0) {
        const float4 v = *(const float4*)&x[((size_t)(b * 4096 + tp - 1) << 8) + c4];
        h.x = f2bf(v.x); h.y = f2bf(v.y); h.z = f2bf(v.z); h.w = f2bf(v.w);
        lo.x = f2bf(v.x - bf2f(h.x)); lo.y = f2bf(v.y - bf2f(h.y));
        lo.z = f2bf(v.z - bf2f(h.z)); lo.w = f2bf(v.w - bf2f(h.w));
    }
    *(ushort4*)&xh[o] = h;
    *(ushort4*)&xl[o] = lo;
}

// ---------- prep 2: kernel [512][768] -> transposed bf16 hi/lo [768][512]
__global__ __launch_bounds__(256) void split_k(
    const float* __restrict__ kw, unsigned short* __restrict__ bh,
    unsigned short* __restrict__ bl)
{
    int idx = blockIdx.x * 256 + threadIdx.x;      // per (n, k4)
    if (idx >= 768 * 128) return;
    int n = idx >> 7, k4 = (idx & 127) << 2;
    ushort4 h, lo;
    float v0 = kw[(size_t)(k4 + 0) * 768 + n];
    float v1 = kw[(size_t)(k4 + 1) * 768 + n];
    float v2 = kw[(size_t)(k4 + 2) * 768 + n];
    float v3 = kw[(size_t)(k4 + 3) * 768 + n];
    h.x = f2bf(v0); h.y = f2bf(v1); h.z = f2bf(v2); h.w = f2bf(v3);
    lo.x = f2bf(v0 - bf2f(h.x)); lo.y = f2bf(v1 - bf2f(h.y));
    lo.z = f2bf(v2 - bf2f(h.z)); lo.w = f2bf(v3 - bf2f(h.w));
    size_t o = ((size_t)n << 9) + k4;
    *(ushort4*)&bh[o] = h;
    *(ushort4*)&bl[o] = lo;
}

// ---------- main GEMM: 128x128 tile, BK=32, 4 waves (2x2), 16x16x32 bf16 MFMA x3
__global__ __launch_bounds__(256) void conv_gemm(
    const unsigned short* __restrict__ xh, const unsigned short* __restrict__ xl,
    const unsigned short* __restrict__ bth, const unsigned short* __restrict__ btl,
    const float* __restrict__ bias,
    unsigned short* __restrict__ Z, float* __restrict__ F, float* __restrict__ O)
{
    __shared__ unsigned short Ah[4096], Al[4096], Bh[4096], Bl[4096]; // [128][32] each, 8KB
    const int tid = threadIdx.x;
    const int l = tid & 63, w = tid >> 6;
    const int wr = w >> 1, wc = w & 1;
    const int bm = blockIdx.x;            // 0..255  (M tiles)
    const int b  = bm >> 5;               // 32 tiles per batch
    const int t0 = (bm & 31) << 7;
    const int n0 = blockIdx.y << 7;       // 0..640

    f32x4 acc[4][4] = {};

    // staging geometry: per wave, 2 wave-loads per array; LDS linear dest.
    // LDS byte L = w*2048 + i*1024 + l*16 ; row=L>>6 ; slot=(l&3)
    // stored data (row, kslot = slot ^ ((row>>1)&3))  [read-side XOR swizzle]
    const int lr  = l >> 2;               // row within wave-load group
    const int lsl = l & 3;

    for (int kk = 0; kk < 16; ++kk) {
        #pragma unroll
        for (int i = 0; i < 2; ++i) {
            const int row = w * 32 + i * 16 + lr;
            const int k0e = (lsl ^ ((row >> 1) & 3)) << 3;
            size_t ga = ((size_t)(b * 4097 + t0 + row + (kk >= 8 ? 1 : 0)) << 8)
                      + ((kk & 7) << 5) + k0e;
            size_t gb = ((size_t)(n0 + row) << 9) + (kk << 5) + k0e;
            const int lb = w * 1024 + i * 512;   // ushort units
            gload16(xh  + ga, &Ah[lb]);
            gload16(xl  + ga, &Al[lb]);
            gload16(bth + gb, &Bh[lb]);
            gload16(btl + gb, &Bl[lb]);
        }
        __syncthreads();

        bf16x8 fah[4], fal[4], fbh[4], fbl[4];
        const int ke = (l >> 4) << 3;     // k elem base for frags
        #pragma unroll
        for (int mi = 0; mi < 4; ++mi) {
            int row = wr * 64 + mi * 16 + (l & 15);
            int byt = ((row << 6) + (ke << 1)) ^ (((row >> 1) & 3) << 4);
            fah[mi] = *(bf16x8*)((char*)Ah + byt);
            fal[mi] = *(bf16x8*)((char*)Al + byt);
        }
        #pragma unroll
        for (int ni = 0; ni < 4; ++ni) {
            int row = wc * 64 + ni * 16 + (l & 15);
            int byt = ((row << 6) + (ke << 1)) ^ (((row >> 1) & 3) << 4);
            fbh[ni] = *(bf16x8*)((char*)Bh + byt);
            fbl[ni] = *(bf16x8*)((char*)Bl + byt);
        }
        #pragma unroll
        for (int mi = 0; mi < 4; ++mi)
            #pragma unroll
            for (int ni = 0; ni < 4; ++ni) {
                acc[mi][ni] = __builtin_amdgcn_mfma_f32_16x16x32_bf16(
                    fah[mi], fbh[ni], acc[mi][ni], 0, 0, 0);
                acc[mi][ni] = __builtin_amdgcn_mfma_f32_16x16x32_bf16(
                    fal[mi], fbh[ni], acc[mi][ni], 0, 0, 0);
                acc[mi][ni] = __builtin_amdgcn_mfma_f32_16x16x32_bf16(
                    fah[mi], fbl[ni], acc[mi][ni], 0, 0, 0);
            }
        __syncthreads();
    }

    // epilogue: bias + activation, scatter to gate arrays
    const int gsel = (int)(blockIdx.y >> 1);   // 0:z 1:f 2:o (uniform per block)
    #pragma unroll
    for (int ni = 0; ni < 4; ++ni) {
        const int ng = n0 + wc * 64 + ni * 16 + (l & 15);
        const float bv = bias[ng];
        const int u = ng & 255;
        #pragma unroll
        for (int mi = 0; mi < 4; ++mi) {
            #pragma unroll
            for (int r = 0; r < 4; ++r) {
                const int t = t0 + wr * 64 + mi * 16 + ((l >> 4) << 2) + r;
                const float g = acc[mi][ni][r] + bv;
                const size_t o = ((size_t)(b * 4096 + t) << 8) + u;
                if (gsel == 0)      Z[o] = f2bf(tanh_fast(g));
                else if (gsel == 1) F[o] = sigmoidf_(g);
                else                O[o] = sigmoidf_(g);
            }
        }
    }
}

// ---------- scan kernels
__global__ __launch_bounds__(256) void chunk_reduce(
    const unsigned short* __restrict__ Z, const float* __restrict__ F,
    float* __restrict__ CA, float* __restrict__ CB)
{
    const int u = threadIdx.x;
    const int blk = blockIdx.x;
    const int b = blk >> 6, ck = blk & 63;
    size_t base = (((size_t)b << 12) + ck * Lq) * 256 + u;
    float A = 1.f, Bv = 0.f;
    #pragma unroll 8
    for (int s = 0; s < Lq; ++s) {
        float f = F[base + (size_t)s * 256];
        float z = bf2f(Z[base + (size_t)s * 256]);
        Bv = fmaf(f, Bv, (1.f - f) * z);
        A *= f;
    }
    size_t cidx = ((size_t)b * NCq + ck) * 256 + u;
    CA[cidx] = A;
    CB[cidx] = Bv;
}

__global__ __launch_bounds__(256) void carry_scan(
    const float* __restrict__ CA, const float* __restrict__ CB,
    float* __restrict__ CIN)
{
    const int u = threadIdx.x;
    const int b = blockIdx.x;
    float c = 0.f;
    #pragma unroll 8
    for (int k = 0; k < NCq; ++k) {
        size_t idx = ((size_t)b * NCq + k) * 256 + u;
        CIN[idx] = c;
        c = fmaf(CA[idx], c, CB[idx]);
    }
}

__global__ __launch_bounds__(256) void apply_scan(
    const unsigned short* __restrict__ Z, const float* __restrict__ F,
    const float* __restrict__ CIN, float* __restrict__ O)
{
    const int u = threadIdx.x;
    const int blk = blockIdx.x;
    const int b = blk >> 6, ck = blk & 63;
    float c = CIN[((size_t)b * NCq + ck) * 256 + u];
    size_t base = (((size_t)b << 12) + ck * Lq) * 256 + u;
    #pragma unroll 8
    for (int s = 0; s < Lq; ++s) {
        size_t idx = base + (size_t)s * 256;
        float f = F[idx], z = bf2f(Z[idx]);
        c = fmaf(f, c, (1.f - f) * z);
        O[idx] = O[idx] * c;
    }
}

extern "C" void kernel_launch(void* const* d_in, const int* in_sizes, int n_in,
                              void* d_out, int out_size, void* d_ws, size_t ws_size,
                              hipStream_t stream) {
    const float* x    = (const float*)d_in[0];
    const float* kw   = (const float*)d_in[1];
    const float* bias = (const float*)d_in[2];
    float* out = (float*)d_out;

    char* p = (char*)d_ws;
    unsigned short* xh  = (unsigned short*)p; p += (size_t)Bq * 4097 * 256 * 2;
    unsigned short* xl  = (unsigned short*)p; p += (size_t)Bq * 4097 * 256 * 2;
    unsigned short* bth = (unsigned short*)p; p += (size_t)768 * 512 * 2;
    unsigned short* btl = (unsigned short*)p; p += (size_t)768 * 512 * 2;
    unsigned short* Z   = (unsigned short*)p; p += (size_t)Bq * Tq * 256 * 2;
    float* F   = (float*)p; p += (size_t)Bq * Tq * 256 * 4;
    float* CA  = (float*)p; p += (size_t)Bq * NCq * 256 * 4;
    float* CB  = (float*)p; p += (size_t)Bq * NCq * 256 * 4;
    float* CIN = (float*)p;

    split_x<<<(Bq * 4097 * 64 + 255) / 256, 256, 0, stream>>>(x, xh, xl);
    split_k<<<(768 * 128 + 255) / 256, 256, 0, stream>>>(kw, bth, btl);
    dim3 g1(256, 6);
    conv_gemm<<<g1, 256, 0, stream>>>(xh, xl, bth, btl, bias, Z, F, out);
    chunk_reduce<<<512, 256, 0, stream>>>(Z, F, CA, CB);
    carry_scan<<<Bq, 256, 0, stream>>>(CA, CB, CIN);
    apply_scan<<<512, 256, 0, stream>>>(Z, F, CIN, out);
}

// Round 3
// 124.687 us; speedup vs baseline: 3.2548x; 1.1817x over previous
//
#include <hip/hip_runtime.h>
#include <math.h>

// QRNN: B=8, T=4096, C=256, UNITS=256, WINDOW=2
// gates = concat(x[t-1],x[t]) @ K[512,768] + bias ; z=tanh f=sig o=sig
// c_t = f*c_{t-1} + (1-f)*z_t ; h = sig(o)*c
// GEMM M=32768 K=512 N=768 via fp16 MFMA: A=fp16(x) (1 array),
// B=bh+bl fp16 split (2 arrays), 2 MFMA passes -> ~2^-11 rel product error.
// 128x128 tile, BK=32, double-buffered LDS with 2-phase prefetch.

#define Bq 8
#define Tq 4096
#define NCq 64
#define Lq 64

typedef __attribute__((ext_vector_type(8))) _Float16 f16x8;
typedef __attribute__((ext_vector_type(4))) float f32x4;

__device__ __forceinline__ float sigmoidf_(float x) {
    return 1.f / (1.f + __expf(-x));
}
__device__ __forceinline__ float tanh_fast(float x) {
    return 1.f - 2.f / (__expf(2.f * x) + 1.f);
}
__device__ __forceinline__ void gload16(const void* g, void* l) {
    __builtin_amdgcn_global_load_lds(
        (const __attribute__((address_space(1))) void*)g,
        (__attribute__((address_space(3))) void*)l, 16, 0, 0);
}

// ---------- prep 1: x -> padded fp16 (xp[b][tp][c], tp=t+1, row 0 = zeros)
__global__ __launch_bounds__(256) void split_x(
    const float* __restrict__ x, _Float16* __restrict__ xh)
{
    int idx = blockIdx.x * 256 + threadIdx.x;      // one per 4 elems
    if (idx >= Bq * 4097 * 64) return;
    int b  = idx / (4097 * 64);
    int r  = idx % (4097 * 64);
    int tp = r / 64, c4 = (r % 64) << 2;
    size_t o = ((size_t)(b * 4097 + tp) << 8) + c4;
    _Float16 h4[4] = {(_Float16)0.f, (_Float16)0.f, (_Float16)0.f, (_Float16)0.f};
    if (tp > 0) {
        const float4 v = *(const float4*)&x[((size_t)(b * 4096 + tp - 1) << 8) + c4];
        h4[0] = (_Float16)v.x; h4[1] = (_Float16)v.y;
        h4[2] = (_Float16)v.z; h4[3] = (_Float16)v.w;
    }
    *(ushort4*)&xh[o] = *(ushort4*)h4;
}

// ---------- prep 2: kernel [512][768] -> transposed fp16 hi/lo [768][512]
__global__ __launch_bounds__(256) void split_k(
    const float* __restrict__ kw, _Float16* __restrict__ bh,
    _Float16* __restrict__ bl)
{
    int idx = blockIdx.x * 256 + threadIdx.x;      // per (n, k)
    if (idx >= 768 * 512) return;
    int n = idx >> 9, k = idx & 511;
    float v = kw[(size_t)k * 768 + n];
    _Float16 h  = (_Float16)v;
    _Float16 lo = (_Float16)(v - (float)h);
    size_t o = ((size_t)n << 9) + k;
    bh[o] = h;
    bl[o] = lo;
}

// ---------- main GEMM: 128x128 tile, BK=32, 4 waves (2x2), 16x16x32 f16 MFMA x2
__global__ __launch_bounds__(256) void conv_gemm(
    const _Float16* __restrict__ xh, const _Float16* __restrict__ bth,
    const _Float16* __restrict__ btl, const float* __restrict__ bias,
    _Float16* __restrict__ Z, float* __restrict__ F, _Float16* __restrict__ SO)
{
    __shared__ _Float16 lds[2][3][4096];   // [buf][A,Bh,Bl][128*32], 48KB
    const int tid = threadIdx.x;
    const int l = tid & 63, w = tid >> 6;
    const int wr = w >> 1, wc = w & 1;
    const int bm = blockIdx.x;            // 0..255
    const int b  = bm >> 5;
    const int t0 = (bm & 31) << 7;
    const int n0 = blockIdx.y << 7;       // 0..640

    f32x4 acc[4][4] = {};

    // staging geometry: LDS linear dest; source pre-swizzled so that
    // LDS(row, slot) holds k-group (slot ^ ((row>>1)&3))  [2-way banks = free]
    const int rowT   = tid >> 2;                        // 0..63 (+64 on round 1)
    const int slotSw = (tid & 3) ^ ((rowT >> 1) & 3);
    size_t gaBase = ((size_t)(b * 4097 + t0 + rowT) << 8) + (slotSw << 3);
    size_t gbBase = ((size_t)(n0 + rowT) << 9) + (slotSw << 3);
    const int ldsW = w << 9;   // half units: wave base within array (w*1024 bytes)

    // fragment ds_read byte offsets (constant across K-steps)
    int offA[4], offB[4];
    const int colB = (l >> 4) << 4;
    #pragma unroll
    for (int i = 0; i < 4; ++i) {
        int ra = wr * 64 + i * 16 + (l & 15);
        offA[i] = ((ra << 6) + colB) ^ (((ra >> 1) & 3) << 4);
        int rb = wc * 64 + i * 16 + (l & 15);
        offB[i] = ((rb << 6) + colB) ^ (((rb >> 1) & 3) << 4);
    }

    auto stage = [&](int buf, int kk) {
        size_t ga = gaBase + (size_t)kk * 32;   // uniform stride over both windows
        size_t gb = gbBase + (size_t)kk * 32;
        _Float16* pA = &lds[buf][0][ldsW];
        _Float16* pB = &lds[buf][1][ldsW];
        _Float16* pL = &lds[buf][2][ldsW];
        gload16(xh  + ga,          pA);
        gload16(xh  + ga + 16384,  pA + 2048);   // rows +64 (A row = 256 halfs)
        gload16(bth + gb,          pB);
        gload16(bth + gb + 32768,  pB + 2048);   // rows +64 (B row = 512 halfs)
        gload16(btl + gb,          pL);
        gload16(btl + gb + 32768,  pL + 2048);
    };

    auto compute = [&](int buf) {
        const char* bA = (const char*)lds[buf][0];
        const char* bH = (const char*)lds[buf][1];
        const char* bL = (const char*)lds[buf][2];
        f16x8 fa[4], fh[4], fl[4];
        #pragma unroll
        for (int i = 0; i < 4; ++i) {
            fa[i] = *(const f16x8*)(bA + offA[i]);
            fh[i] = *(const f16x8*)(bH + offB[i]);
            fl[i] = *(const f16x8*)(bL + offB[i]);
        }
        #pragma unroll
        for (int mi = 0; mi < 4; ++mi)
            #pragma unroll
            for (int ni = 0; ni < 4; ++ni) {
                acc[mi][ni] = __builtin_amdgcn_mfma_f32_16x16x32_f16(
                    fa[mi], fh[ni], acc[mi][ni], 0, 0, 0);
                acc[mi][ni] = __builtin_amdgcn_mfma_f32_16x16x32_f16(
                    fa[mi], fl[ni], acc[mi][ni], 0, 0, 0);
            }
    };

    stage(0, 0);
    __syncthreads();
    int buf = 0;
    for (int kk = 0; kk < 15; ++kk) {
        stage(buf ^ 1, kk + 1);   // issue prefetch BEFORE compute
        compute(buf);
        __syncthreads();          // drains vmcnt (prefetch) + lgkm
        buf ^= 1;
    }
    compute(buf);

    // epilogue: bias + activation, scatter to gate arrays
    const int gsel = (int)(blockIdx.y >> 1);   // 0:z 1:f 2:o (uniform per block)
    #pragma unroll
    for (int ni = 0; ni < 4; ++ni) {
        const int ng = n0 + wc * 64 + ni * 16 + (l & 15);
        const float bv = bias[ng];
        const int u = ng & 255;
        #pragma unroll
        for (int mi = 0; mi < 4; ++mi) {
            #pragma unroll
            for (int r = 0; r < 4; ++r) {
                const int t = t0 + wr * 64 + mi * 16 + ((l >> 4) << 2) + r;
                const float g = acc[mi][ni][r] + bv;
                const size_t o = ((size_t)(b * 4096 + t) << 8) + u;
                if (gsel == 0)      Z[o]  = (_Float16)tanh_fast(g);
                else if (gsel == 1) F[o]  = sigmoidf_(g);
                else                SO[o] = (_Float16)sigmoidf_(g);
            }
        }
    }
}

// ---------- scan kernels
__global__ __launch_bounds__(256) void chunk_reduce(
    const _Float16* __restrict__ Z, const float* __restrict__ F,
    float* __restrict__ CA, float* __restrict__ CB)
{
    const int u = threadIdx.x;
    const int blk = blockIdx.x;
    const int b = blk >> 6, ck = blk & 63;
    size_t base = (((size_t)b << 12) + ck * Lq) * 256 + u;
    float A = 1.f, Bv = 0.f;
    #pragma unroll 8
    for (int s = 0; s < Lq; ++s) {
        float f = F[base + (size_t)s * 256];
        float z = (float)Z[base + (size_t)s * 256];
        Bv = fmaf(f, Bv, (1.f - f) * z);
        A *= f;
    }
    size_t cidx = ((size_t)b * NCq + ck) * 256 + u;
    CA[cidx] = A;
    CB[cidx] = Bv;
}

__global__ __launch_bounds__(256) void carry_scan(
    const float* __restrict__ CA, const float* __restrict__ CB,
    float* __restrict__ CIN)
{
    const int u = threadIdx.x;
    const int b = blockIdx.x;
    float c = 0.f;
    #pragma unroll 8
    for (int k = 0; k < NCq; ++k) {
        size_t idx = ((size_t)b * NCq + k) * 256 + u;
        CIN[idx] = c;
        c = fmaf(CA[idx], c, CB[idx]);
    }
}

__global__ __launch_bounds__(256) void apply_scan(
    const _Float16* __restrict__ Z, const float* __restrict__ F,
    const _Float16* __restrict__ SO, const float* __restrict__ CIN,
    float* __restrict__ out)
{
    const int u = threadIdx.x;
    const int blk = blockIdx.x;
    const int b = blk >> 6, ck = blk & 63;
    float c = CIN[((size_t)b * NCq + ck) * 256 + u];
    size_t base = (((size_t)b << 12) + ck * Lq) * 256 + u;
    #pragma unroll 8
    for (int s = 0; s < Lq; ++s) {
        size_t idx = base + (size_t)s * 256;
        float f = F[idx], z = (float)Z[idx];
        c = fmaf(f, c, (1.f - f) * z);
        out[idx] = (float)SO[idx] * c;
    }
}

extern "C" void kernel_launch(void* const* d_in, const int* in_sizes, int n_in,
                              void* d_out, int out_size, void* d_ws, size_t ws_size,
                              hipStream_t stream) {
    const float* x    = (const float*)d_in[0];
    const float* kw   = (const float*)d_in[1];
    const float* bias = (const float*)d_in[2];
    float* out = (float*)d_out;

    char* p = (char*)d_ws;
    _Float16* xh  = (_Float16*)p; p += (size_t)Bq * 4097 * 256 * 2;
    _Float16* bth = (_Float16*)p; p += (size_t)768 * 512 * 2;
    _Float16* btl = (_Float16*)p; p += (size_t)768 * 512 * 2;
    _Float16* Z   = (_Float16*)p; p += (size_t)Bq * Tq * 256 * 2;
    float*    F   = (float*)p;    p += (size_t)Bq * Tq * 256 * 4;
    _Float16* SO  = (_Float16*)p; p += (size_t)Bq * Tq * 256 * 2;
    float* CA  = (float*)p; p += (size_t)Bq * NCq * 256 * 4;
    float* CB  = (float*)p; p += (size_t)Bq * NCq * 256 * 4;
    float* CIN = (float*)p;

    split_x<<<(Bq * 4097 * 64 + 255) / 256, 256, 0, stream>>>(x, xh);
    split_k<<<(768 * 512 + 255) / 256, 256, 0, stream>>>(kw, bth, btl);
    dim3 g1(256, 6);
    conv_gemm<<<g1, 256, 0, stream>>>(xh, bth, btl, bias, Z, F, SO);
    chunk_reduce<<<512, 256, 0, stream>>>(Z, F, CA, CB);
    carry_scan<<<Bq, 256, 0, stream>>>(CA, CB, CIN);
    apply_scan<<<512, 256, 0, stream>>>(Z, F, SO, CIN, out);
}

// Round 4
// 93.447 us; speedup vs baseline: 4.3430x; 1.3343x over previous
//
#include <hip/hip_runtime.h>
#include <math.h>

// QRNN: B=8, T=4096, C=256, UNITS=256, WINDOW=2
// gates = concat(x[t-1],x[t]) @ K[512,768] + bias ; z=tanh f=sig o=sig
// c_t = f*c_{t-1} + (1-f)*z_t ; h = sig(o)*c
// GEMM M=32768 K=512 N=768 via single-pass fp16 MFMA (err ~5e-4 << 0.019 thr).
// 128x128 tile, BK=32, double-buffered LDS, LDS-transposed coalesced epilogue.

#define Bq 8
#define Tq 4096
#define NCq 64
#define Lq 64

typedef __attribute__((ext_vector_type(8))) _Float16 f16x8;
typedef __attribute__((ext_vector_type(4))) float f32x4;

__device__ __forceinline__ float sigmoidf_(float x) {
    return 1.f / (1.f + __expf(-x));
}
__device__ __forceinline__ float tanh_fast(float x) {
    return 1.f - 2.f / (__expf(2.f * x) + 1.f);
}
__device__ __forceinline__ unsigned short f16b(float a) {
    _Float16 h = (_Float16)a;
    return *(unsigned short*)&h;
}
__device__ __forceinline__ unsigned packf(float f) {
    _Float16 h = (_Float16)f;
    _Float16 lo = (_Float16)(f - (float)h);
    return ((unsigned)*(unsigned short*)&h << 16) | *(unsigned short*)&lo;
}
__device__ __forceinline__ float unpackf(unsigned p) {
    unsigned short hu = p >> 16, lu = p & 0xffffu;
    return (float)*(_Float16*)&hu + (float)*(_Float16*)&lu;
}
__device__ __forceinline__ void gload16(const void* g, void* l) {
    __builtin_amdgcn_global_load_lds(
        (const __attribute__((address_space(1))) void*)g,
        (__attribute__((address_space(3))) void*)l, 16, 0, 0);
}

// ---------- prep 1: x -> padded fp16 (xp[b][tp][c], tp=t+1, row 0 = zeros)
__global__ __launch_bounds__(256) void split_x(
    const float* __restrict__ x, _Float16* __restrict__ xh)
{
    int idx = blockIdx.x * 256 + threadIdx.x;      // one per 4 elems
    if (idx >= Bq * 4097 * 64) return;
    int b  = idx / (4097 * 64);
    int r  = idx % (4097 * 64);
    int tp = r / 64, c4 = (r % 64) << 2;
    size_t o = ((size_t)(b * 4097 + tp) << 8) + c4;
    _Float16 h4[4] = {(_Float16)0.f, (_Float16)0.f, (_Float16)0.f, (_Float16)0.f};
    if (tp > 0) {
        const float4 v = *(const float4*)&x[((size_t)(b * 4096 + tp - 1) << 8) + c4];
        h4[0] = (_Float16)v.x; h4[1] = (_Float16)v.y;
        h4[2] = (_Float16)v.z; h4[3] = (_Float16)v.w;
    }
    *(ushort4*)&xh[o] = *(ushort4*)h4;
}

// ---------- prep 2: kernel [512][768] -> transposed fp16 [768][512]
__global__ __launch_bounds__(256) void split_k(
    const float* __restrict__ kw, _Float16* __restrict__ bh)
{
    int idx = blockIdx.x * 256 + threadIdx.x;      // per (n, k)
    if (idx >= 768 * 512) return;
    int n = idx >> 9, k = idx & 511;
    bh[((size_t)n << 9) + k] = (_Float16)kw[(size_t)k * 768 + n];
}

// ---------- main GEMM: 128x128 tile, BK=32, 4 waves (2x2), 16x16x32 f16 MFMA
__global__ __launch_bounds__(256) void conv_gemm(
    const _Float16* __restrict__ xh, const _Float16* __restrict__ bth,
    const float* __restrict__ bias,
    _Float16* __restrict__ Z, unsigned* __restrict__ Fp, _Float16* __restrict__ SO)
{
    __shared__ _Float16 lds[2][2][4096];   // [buf][A,B][128*32], 32KB
    const int tid = threadIdx.x;
    const int l = tid & 63, w = tid >> 6;
    const int wr = w >> 1, wc = w & 1;
    const int bm = blockIdx.x;            // 0..255
    const int b  = bm >> 5;
    const int t0 = (bm & 31) << 7;
    const int n0 = blockIdx.y << 7;       // 0..640

    f32x4 acc[4][4] = {};

    // staging: LDS linear dest; source pre-swizzled so LDS(row, slot) holds
    // k-group (slot ^ ((row>>1)&3))
    const int rowT   = tid >> 2;
    const int slotSw = (tid & 3) ^ ((rowT >> 1) & 3);   // (row+64) keeps (row>>1)&3
    size_t gaBase = ((size_t)(b * 4097 + t0 + rowT) << 8) + (slotSw << 3);
    size_t gbBase = ((size_t)(n0 + rowT) << 9) + (slotSw << 3);
    const int ldsW = w << 9;   // halves: wave base (w*1024 bytes)

    int offA[4], offB[4];
    const int colB = (l >> 4) << 4;
    #pragma unroll
    for (int i = 0; i < 4; ++i) {
        int ra = wr * 64 + i * 16 + (l & 15);
        offA[i] = ((ra << 6) + colB) ^ (((ra >> 1) & 3) << 4);
        int rb = wc * 64 + i * 16 + (l & 15);
        offB[i] = ((rb << 6) + colB) ^ (((rb >> 1) & 3) << 4);
    }

    auto stage = [&](int buf, int kk) {
        size_t ga = gaBase + (size_t)kk * 32;
        size_t gb = gbBase + (size_t)kk * 32;
        _Float16* pA = &lds[buf][0][ldsW];
        _Float16* pB = &lds[buf][1][ldsW];
        gload16(xh  + ga,          pA);
        gload16(xh  + ga + 16384,  pA + 2048);   // rows +64 (A row = 256 halves)
        gload16(bth + gb,          pB);
        gload16(bth + gb + 32768,  pB + 2048);   // rows +64 (B row = 512 halves)
    };

    auto compute = [&](int buf) {
        const char* bA = (const char*)lds[buf][0];
        const char* bB = (const char*)lds[buf][1];
        f16x8 fa[4], fb[4];
        #pragma unroll
        for (int i = 0; i < 4; ++i) {
            fa[i] = *(const f16x8*)(bA + offA[i]);
            fb[i] = *(const f16x8*)(bB + offB[i]);
        }
        #pragma unroll
        for (int mi = 0; mi < 4; ++mi)
            #pragma unroll
            for (int ni = 0; ni < 4; ++ni)
                acc[mi][ni] = __builtin_amdgcn_mfma_f32_16x16x32_f16(
                    fa[mi], fb[ni], acc[mi][ni], 0, 0, 0);
    };

    stage(0, 0);
    __syncthreads();
    int buf = 0;
    for (int kk = 0; kk < 15; ++kk) {
        stage(buf ^ 1, kk + 1);   // prefetch before compute
        compute(buf);
        __syncthreads();
        buf ^= 1;
    }
    compute(buf);
    __syncthreads();              // before reusing LDS for epilogue

    // ---- epilogue ----
    const int gsel = (int)(blockIdx.y >> 1);   // 0:z 1:f 2:o
    float bb[4];
    #pragma unroll
    for (int ni = 0; ni < 4; ++ni)
        bb[ni] = bias[n0 + wc * 64 + ni * 16 + (l & 15)];

    if (gsel == 1) {
        // F: exact fp16 hi/lo pair packed in uint, direct stores (64B runs)
        #pragma unroll
        for (int ni = 0; ni < 4; ++ni) {
            const int u = (n0 - 256) + wc * 64 + ni * 16 + (l & 15);
            #pragma unroll
            for (int mi = 0; mi < 4; ++mi)
                #pragma unroll
                for (int r = 0; r < 4; ++r) {
                    const int t = t0 + wr * 64 + mi * 16 + ((l >> 4) << 2) + r;
                    float f = sigmoidf_(acc[mi][ni][r] + bb[ni]);
                    Fp[((size_t)(b * 4096 + t) << 8) + u] = packf(f);
                }
        }
    } else {
        // Z / SO: fp16 via LDS transpose, 256B-run coalesced stores
        unsigned short* Hd = (unsigned short*)&lds[0][0][0];   // 32KB tile
        #pragma unroll
        for (int ni = 0; ni < 4; ++ni) {
            const int cl = wc * 64 + ni * 16 + (l & 15);
            #pragma unroll
            for (int mi = 0; mi < 4; ++mi)
                #pragma unroll
                for (int r = 0; r < 4; ++r) {
                    const int trl = wr * 64 + mi * 16 + ((l >> 4) << 2) + r;
                    float g = acc[mi][ni][r] + bb[ni];
                    float a = (gsel == 0) ? tanh_fast(g) : sigmoidf_(g);
                    int byt = (trl << 8) + ((cl << 1) ^ (((trl >> 2) & 3) << 4));
                    *(unsigned short*)((char*)Hd + byt) = f16b(a);
                }
        }
        __syncthreads();
        _Float16* Gg = (gsel == 0) ? Z : SO;
        const int u0 = (gsel == 0) ? n0 : (n0 - 512);
        const size_t gbase = ((size_t)(b * 4096 + t0) << 8) + u0;  // halves
        #pragma unroll
        for (int j = 0; j < 8; ++j) {
            int hoff = tid * 8 + j * 2048;         // halves
            int row  = hoff >> 7;
            int colB = (hoff & 127) << 1;          // bytes within row
            int srcB = (row << 8) + (colB ^ (((row >> 2) & 3) << 4));
            int4 v = *(const int4*)((const char*)Hd + srcB);
            *(int4*)&Gg[gbase + ((size_t)row << 8) + (colB >> 1)] = v;
        }
    }
}

// ---------- scan kernels
__global__ __launch_bounds__(256) void chunk_reduce(
    const _Float16* __restrict__ Z, const unsigned* __restrict__ Fp,
    float* __restrict__ CA, float* __restrict__ CB)
{
    const int u = threadIdx.x;
    const int blk = blockIdx.x;
    const int b = blk >> 6, ck = blk & 63;
    size_t base = (((size_t)b << 12) + ck * Lq) * 256 + u;
    float A = 1.f, Bv = 0.f;
    #pragma unroll 8
    for (int s = 0; s < Lq; ++s) {
        float f = unpackf(Fp[base + (size_t)s * 256]);
        float z = (float)Z[base + (size_t)s * 256];
        Bv = fmaf(f, Bv, (1.f - f) * z);
        A *= f;
    }
    size_t cidx = ((size_t)b * NCq + ck) * 256 + u;
    CA[cidx] = A;
    CB[cidx] = Bv;
}

__global__ __launch_bounds__(256) void carry_scan(
    const float* __restrict__ CA, const float* __restrict__ CB,
    float* __restrict__ CIN)
{
    const int u = threadIdx.x;
    const int b = blockIdx.x;
    float c = 0.f;
    #pragma unroll 8
    for (int k = 0; k < NCq; ++k) {
        size_t idx = ((size_t)b * NCq + k) * 256 + u;
        CIN[idx] = c;
        c = fmaf(CA[idx], c, CB[idx]);
    }
}

__global__ __launch_bounds__(256) void apply_scan(
    const _Float16* __restrict__ Z, const unsigned* __restrict__ Fp,
    const _Float16* __restrict__ SO, const float* __restrict__ CIN,
    float* __restrict__ out)
{
    const int u = threadIdx.x;
    const int blk = blockIdx.x;
    const int b = blk >> 6, ck = blk & 63;
    float c = CIN[((size_t)b * NCq + ck) * 256 + u];
    size_t base = (((size_t)b << 12) + ck * Lq) * 256 + u;
    #pragma unroll 8
    for (int s = 0; s < Lq; ++s) {
        size_t idx = base + (size_t)s * 256;
        float f = unpackf(Fp[idx]), z = (float)Z[idx];
        c = fmaf(f, c, (1.f - f) * z);
        out[idx] = (float)SO[idx] * c;
    }
}

extern "C" void kernel_launch(void* const* d_in, const int* in_sizes, int n_in,
                              void* d_out, int out_size, void* d_ws, size_t ws_size,
                              hipStream_t stream) {
    const float* x    = (const float*)d_in[0];
    const float* kw   = (const float*)d_in[1];
    const float* bias = (const float*)d_in[2];
    float* out = (float*)d_out;

    char* p = (char*)d_ws;
    _Float16* xh  = (_Float16*)p; p += (size_t)Bq * 4097 * 256 * 2;
    _Float16* bth = (_Float16*)p; p += (size_t)768 * 512 * 2;
    _Float16* Z   = (_Float16*)p; p += (size_t)Bq * Tq * 256 * 2;
    unsigned* Fp  = (unsigned*)p; p += (size_t)Bq * Tq * 256 * 4;
    _Float16* SO  = (_Float16*)p; p += (size_t)Bq * Tq * 256 * 2;
    float* CA  = (float*)p; p += (size_t)Bq * NCq * 256 * 4;
    float* CB  = (float*)p; p += (size_t)Bq * NCq * 256 * 4;
    float* CIN = (float*)p;

    split_x<<<(Bq * 4097 * 64 + 255) / 256, 256, 0, stream>>>(x, xh);
    split_k<<<(768 * 512 + 255) / 256, 256, 0, stream>>>(kw, bth);
    dim3 g1(256, 6);
    conv_gemm<<<g1, 256, 0, stream>>>(xh, bth, bias, Z, Fp, out ? (_Float16*)((char*)d_ws + ((size_t)Bq*4097*256*2 + (size_t)768*512*2 + (size_t)Bq*Tq*256*2 + (size_t)Bq*Tq*256*4)) : nullptr);
    chunk_reduce<<<512, 256, 0, stream>>>(Z, Fp, CA, CB);
    carry_scan<<<Bq, 256, 0, stream>>>(CA, CB, CIN);
    apply_scan<<<512, 256, 0, stream>>>(Z, Fp, SO, CIN, out);
}